// Round 13
// baseline (1391.448 us; speedup 1.0000x reference)
//
#include <hip/hip_runtime.h>
#include <math.h>

static constexpr float EPS_SK = 0.02f;
static constexpr float LOG2E  = 1.4426950408889634f;
static constexpr float LN2F   = 0.6931471805599453f;
#define LOGN1 6.931471805599453f   /* log 1024 */
#define LOGN2 8.317766166719343f   /* log 4096 */

__device__ __forceinline__ float fexp2(float x){ return __builtin_amdgcn_exp2f(x); }
__device__ __forceinline__ float flog2(float x){ return __builtin_amdgcn_logf(x); }

using f32x2 = __attribute__((ext_vector_type(2))) float;

// ============ LDS union padded >80KB => exactly 1 block/CU; 194 blocks co-resident ====
union Lds {
  struct {
    float sx[4096], sy[4096], sz[4096];      // 48 KB staged points (SoA for pk loads)
    float obx[1024], oby[1024], obz[1024];   // 12 KB selected-point buffer
    unsigned long long K[2][8];              // parity-buffered wave winner keys
    float4 C4[2][8];                         // parity-buffered wave winner coords
  } fps;
  struct { float tyx[1024], tyy[1024], tyz[1024], tg[1024]; } emd;
  struct { float x[1024], y[1024], z[1024]; } ch;
  float pad[21000];                          // 84000 B -> 1 block/CU
};

// ---------------- sync primitives (validated R5-R12) ----------------
__device__ __forceinline__ void gbar(unsigned* cnt, unsigned* gen, unsigned nblk) {
  __threadfence();
  __syncthreads();
  if (threadIdx.x == 0) {
    unsigned g = __hip_atomic_load(gen, __ATOMIC_ACQUIRE, __HIP_MEMORY_SCOPE_AGENT);
    if (__hip_atomic_fetch_add(cnt, 1u, __ATOMIC_ACQ_REL, __HIP_MEMORY_SCOPE_AGENT) == nblk - 1u) {
      __hip_atomic_store(cnt, 0u, __ATOMIC_RELAXED, __HIP_MEMORY_SCOPE_AGENT);
      __hip_atomic_fetch_add(gen, 1u, __ATOMIC_ACQ_REL, __HIP_MEMORY_SCOPE_AGENT);
    } else {
      while (__hip_atomic_load(gen, __ATOMIC_ACQUIRE, __HIP_MEMORY_SCOPE_AGENT) == g)
        __builtin_amdgcn_s_sleep(8);
    }
  }
  __syncthreads();
  __threadfence();
}

__device__ __forceinline__ void signal_done(unsigned* f) {
  __threadfence();
  __syncthreads();
  if (threadIdx.x == 0)
    __hip_atomic_fetch_add(f, 1u, __ATOMIC_RELEASE, __HIP_MEMORY_SCOPE_AGENT);
}

__device__ __forceinline__ void waitcnt_ge(unsigned* f, unsigned target) {
  if (threadIdx.x == 0)
    while (__hip_atomic_load(f, __ATOMIC_ACQUIRE, __HIP_MEMORY_SCOPE_AGENT) < target)
      __builtin_amdgcn_s_sleep(16);
  __syncthreads();
  __threadfence();
}

// DPP helper (old=self => invalid lanes are no-ops); chain accumulates to lane 63
template<int C>
__device__ __forceinline__ float dppf(float x) {
  return __int_as_float(__builtin_amdgcn_update_dpp(
      __float_as_int(x), __float_as_int(x), C, 0xF, 0xF, false));
}
__device__ __forceinline__ float wave_max_to_l63(float v) {
  v = fmaxf(v, dppf<0x111>(v));  // row_shr:1
  v = fmaxf(v, dppf<0x112>(v));  // row_shr:2
  v = fmaxf(v, dppf<0x114>(v));  // row_shr:4
  v = fmaxf(v, dppf<0x118>(v));  // row_shr:8
  v = fmaxf(v, dppf<0x142>(v));  // row_bcast15
  v = fmaxf(v, dppf<0x143>(v));  // row_bcast31
  return v;
}
__device__ __forceinline__ unsigned long long u64max(unsigned long long a, unsigned long long b) {
  return a > b ? a : b;
}

// ---------------- FPS body: 512 threads (8 waves), 8 pts/lane as 4 f32x2 pairs ------
// pk distance update + value-only DPP max + ballot/ff1/readlane index resolve.
// Winning lane writes (key, coords) to the slot => NO dependent LDS broadcast
// read after the cross-wave tree (coords selected in-register via 8 predicated moves).
__device__ __forceinline__ void fps_body(Lds& L, const float* __restrict__ gt,
                                         float* __restrict__ gt_fps, int b) {
  const int t = threadIdx.x;
  const int lane = t & 63;
  const int wv   = t >> 6;
  const float* P = gt + (size_t)b*4096*3;
  for (int i = t; i < 4096; i += 512) {
    L.fps.sx[i] = P[i*3+0]; L.fps.sy[i] = P[i*3+1]; L.fps.sz[i] = P[i*3+2];
  }
  __syncthreads();
  // global idx = t*8 + 2*p + half  (ascending in (p, half) for fixed t; lane ranges
  // within a wave are disjoint ascending => first matching lane = wave-min index)
  f32x2 px[4], py[4], pz[4], d2[4];
#pragma unroll
  for (int p = 0; p < 4; ++p) {
    const int i0 = t*8 + 2*p;
    px[p] = *(const f32x2*)&L.fps.sx[i0];
    py[p] = *(const f32x2*)&L.fps.sy[i0];
    pz[p] = *(const f32x2*)&L.fps.sz[i0];
    d2[p].x = 1e10f; d2[p].y = 1e10f;        // matches reference init
  }
  float cx = L.fps.sx[0], cy = L.fps.sy[0], cz = L.fps.sz[0];
  if (t == 0) { L.fps.obx[0] = cx; L.fps.oby[0] = cy; L.fps.obz[0] = cz; }
  for (int s = 1; s < 1024; ++s) {
    f32x2 nd0, nd1, nd2, nd3;
    {
#pragma clang fp contract(off)
      f32x2 c2x; c2x.x = cx; c2x.y = cx;
      f32x2 c2y; c2y.x = cy; c2y.y = cy;
      f32x2 c2z; c2z.x = cz; c2z.y = cz;
      f32x2 dx, dy, dz, d;
      dx = px[0]-c2x; dy = py[0]-c2y; dz = pz[0]-c2z;
      d = dx*dx + dy*dy + dz*dz;  nd0 = __builtin_elementwise_min(d2[0], d); d2[0] = nd0;
      dx = px[1]-c2x; dy = py[1]-c2y; dz = pz[1]-c2z;
      d = dx*dx + dy*dy + dz*dz;  nd1 = __builtin_elementwise_min(d2[1], d); d2[1] = nd1;
      dx = px[2]-c2x; dy = py[2]-c2y; dz = pz[2]-c2z;
      d = dx*dx + dy*dy + dz*dz;  nd2 = __builtin_elementwise_min(d2[2], d); d2[2] = nd2;
      dx = px[3]-c2x; dy = py[3]-c2y; dz = pz[3]-c2z;
      d = dx*dx + dy*dy + dz*dz;  nd3 = __builtin_elementwise_min(d2[3], d); d2[3] = nd3;
    }
    // tree-shaped running max
    f32x2 m01 = __builtin_elementwise_max(nd0, nd1);
    f32x2 m23 = __builtin_elementwise_max(nd2, nd3);
    f32x2 m03 = __builtin_elementwise_max(m01, m23);
    float bv = fmaxf(m03.x, m03.y);
    bv = wave_max_to_l63(bv);
    const unsigned Mbits = (unsigned)__builtin_amdgcn_readlane(__float_as_int(bv), 63);
    const float M = __uint_as_float(Mbits);
    // per-lane first-match index (local indices ascend with (p,half))
    int icl = 0x7FFFFFFF;
#pragma unroll
    for (int p = 0; p < 4; ++p) {
      const int i0 = t*8 + 2*p;
      if (d2[p].x == M) icl = min(icl, i0);
      if (d2[p].y == M) icl = min(icl, i0 + 1);
    }
    unsigned long long mk = __ballot(icl != 0x7FFFFFFF);
    const int sl0 = __builtin_ctzll(mk);               // first matching lane (SGPR)
    const int widx = __builtin_amdgcn_readlane(icl, sl0);
    const int pb = s & 1;
    if (lane == sl0) {
      // priority-select the first matching point's coords from own registers
      float wx = px[3].y, wy = py[3].y, wz = pz[3].y;
      if (d2[3].x == M) { wx = px[3].x; wy = py[3].x; wz = pz[3].x; }
      if (d2[2].y == M) { wx = px[2].y; wy = py[2].y; wz = pz[2].y; }
      if (d2[2].x == M) { wx = px[2].x; wy = py[2].x; wz = pz[2].x; }
      if (d2[1].y == M) { wx = px[1].y; wy = py[1].y; wz = pz[1].y; }
      if (d2[1].x == M) { wx = px[1].x; wy = py[1].x; wz = pz[1].x; }
      if (d2[0].y == M) { wx = px[0].y; wy = py[0].y; wz = pz[0].y; }
      if (d2[0].x == M) { wx = px[0].x; wy = py[0].x; wz = pz[0].x; }
      L.fps.K[pb][wv] = (((unsigned long long)Mbits) << 32)
                        | (unsigned)(~widx);  // bigger = bigger val or smaller idx
      L.fps.C4[pb][wv] = make_float4(wx, wy, wz, 0.0f);
    }
    __syncthreads();
    ulonglong2 k0 = *(const ulonglong2*)&L.fps.K[pb][0];
    ulonglong2 k1 = *(const ulonglong2*)&L.fps.K[pb][2];
    ulonglong2 k2 = *(const ulonglong2*)&L.fps.K[pb][4];
    ulonglong2 k3 = *(const ulonglong2*)&L.fps.K[pb][6];
    float4 c0 = L.fps.C4[pb][0], c1 = L.fps.C4[pb][1];
    float4 c2 = L.fps.C4[pb][2], c3 = L.fps.C4[pb][3];
    float4 c4 = L.fps.C4[pb][4], c5 = L.fps.C4[pb][5];
    float4 c6 = L.fps.C4[pb][6], c7 = L.fps.C4[pb][7];
    unsigned long long m0 = u64max(k0.x, k0.y);
    unsigned long long m1 = u64max(k1.x, k1.y);
    unsigned long long m2 = u64max(k2.x, k2.y);
    unsigned long long m3 = u64max(k3.x, k3.y);
    unsigned long long W = u64max(u64max(m0, m1), u64max(m2, m3));
    // keys are unique across waves (disjoint idx ranges) => exactly one match
    float4 cw = c0;
    if (k0.y == W) cw = c1;
    if (k1.x == W) cw = c2;
    if (k1.y == W) cw = c3;
    if (k2.x == W) cw = c4;
    if (k2.y == W) cw = c5;
    if (k3.x == W) cw = c6;
    if (k3.y == W) cw = c7;
    cx = cw.x; cy = cw.y; cz = cw.z;
    if (t == 0) { L.fps.obx[s] = cx; L.fps.oby[s] = cy; L.fps.obz[s] = cz; }
  }
  __syncthreads();
  for (int i = t; i < 1024; i += 512) {      // one bulk global store at the end
    float* o = gt_fps + (size_t)(b*1024 + i)*3;
    o[0] = L.fps.obx[i]; o[1] = L.fps.oby[i]; o[2] = L.fps.obz[i];
  }
}

// ============== EMD bodies, 512 threads, JPW rows/wave, masked row wrap (proven) ====
template<int JPW>
__device__ __forceinline__ void emd_pass_t(
    const float* __restrict__ xb, int xm,
    const float* __restrict__ yb, int ym,
    const float* __restrict__ vinb, float* __restrict__ voutb,
    int N, float logN, int use_vin, int r0b,
    float* tyx, float* tyy, float* tyz, float* tg)
{
  const int t = threadIdx.x;
  const int lane = t & 63;
  const int wv   = t >> 6;
  const int r0 = r0b + wv*JPW;
  float px[JPW], py[JPW], pz[JPW], mx[JPW], sm[JPW];
#pragma unroll
  for (int j = 0; j < JPW; ++j) {
    const int row = (r0 + j) & xm;
    const float* xp = xb + (size_t)row*3;
    px[j] = xp[0]; py[j] = xp[1]; pz[j] = xp[2];
    mx[j] = -3.4e38f; sm[j] = 0.0f;
  }
  const float S = LOG2E / EPS_SK;
  const int ntiles = N >> 10;
  for (int tt = 0; tt < ntiles; ++tt) {
    const int base = tt << 10;
    __syncthreads();
    for (int i = t; i < 1024; i += 512) {
      const int row = (base + i) & ym;
      const float* yp = yb + (size_t)row*3;
      tyx[i] = yp[0]; tyy[i] = yp[1]; tyz[i] = yp[2];
      tg[i]  = use_vin ? vinb[base + i] : 0.0f;
    }
    __syncthreads();
    for (int mi = lane; mi < 1024; mi += 64) {
      float yx = tyx[mi], yy = tyy[mi], yz = tyz[mi], g = tg[mi];
#pragma unroll
      for (int j = 0; j < JPW; ++j) {
        float dx = px[j]-yx, dy = py[j]-yy, dz = pz[j]-yz;
        float d  = dx*dx + dy*dy + dz*dz;
        float tv = (g - d) * S;
        float nm = fmaxf(mx[j], tv);
        sm[j] = sm[j]*fexp2(mx[j]-nm) + fexp2(tv-nm);
        mx[j] = nm;
      }
    }
  }
#pragma unroll
  for (int j = 0; j < JPW; ++j) {
#pragma unroll
    for (int off = 1; off < 64; off <<= 1) {
      float om = __shfl_xor(mx[j], off, 64);
      float os = __shfl_xor(sm[j], off, 64);
      float nm = fmaxf(mx[j], om);
      sm[j] = sm[j]*fexp2(mx[j]-nm) + os*fexp2(om-nm);
      mx[j] = nm;
    }
  }
  if (lane == 0) {
#pragma unroll
    for (int j = 0; j < JPW; ++j) {
      float lse = (mx[j] + flog2(sm[j])) * LN2F;
      voutb[r0 + j] = -EPS_SK * (lse + logN);
    }
  }
}

template<int JPW>
__device__ __forceinline__ void emd_final_t(
    const float* __restrict__ xb, int xm,
    const float* __restrict__ yb, int ym,
    const float* __restrict__ ginb, float* __restrict__ doutb,
    int N, int use_g, int r0b,
    float* tyx, float* tyy, float* tyz, float* tg)
{
  const int t = threadIdx.x;
  const int lane = t & 63;
  const int wv   = t >> 6;
  const int r0 = r0b + wv*JPW;
  float px[JPW], py[JPW], pz[JPW], mx[JPW], sm[JPW], wc[JPW];
#pragma unroll
  for (int j = 0; j < JPW; ++j) {
    const int row = (r0 + j) & xm;
    const float* xp = xb + (size_t)row*3;
    px[j] = xp[0]; py[j] = xp[1]; pz[j] = xp[2];
    mx[j] = -3.4e38f; sm[j] = 0.0f; wc[j] = 0.0f;
  }
  const float S = LOG2E / EPS_SK;
  const int ntiles = N >> 10;
  for (int tt = 0; tt < ntiles; ++tt) {
    const int base = tt << 10;
    __syncthreads();
    for (int i = t; i < 1024; i += 512) {
      const int row = (base + i) & ym;
      const float* yp = yb + (size_t)row*3;
      tyx[i] = yp[0]; tyy[i] = yp[1]; tyz[i] = yp[2];
      tg[i]  = use_g ? ginb[base + i] : 0.0f;
    }
    __syncthreads();
    for (int mi = lane; mi < 1024; mi += 64) {
      float yx = tyx[mi], yy = tyy[mi], yz = tyz[mi], g = tg[mi];
#pragma unroll
      for (int j = 0; j < JPW; ++j) {
        float dx = px[j]-yx, dy = py[j]-yy, dz = pz[j]-yz;
        float d  = dx*dx + dy*dy + dz*dz;
        float tv = (g - d) * S;
        float nm = fmaxf(mx[j], tv);
        float r  = fexp2(mx[j]-nm);
        float e  = fexp2(tv-nm);
        sm[j] = sm[j]*r + e;
        wc[j] = wc[j]*r + e*d;
        mx[j] = nm;
      }
    }
  }
#pragma unroll
  for (int j = 0; j < JPW; ++j) {
#pragma unroll
    for (int off = 1; off < 64; off <<= 1) {
      float om = __shfl_xor(mx[j], off, 64);
      float os = __shfl_xor(sm[j], off, 64);
      float ow = __shfl_xor(wc[j], off, 64);
      float nm = fmaxf(mx[j], om);
      float r1 = fexp2(mx[j]-nm);
      float r2 = fexp2(om-nm);
      sm[j] = sm[j]*r1 + os*r2;
      wc[j] = wc[j]*r1 + ow*r2;
      mx[j] = nm;
    }
  }
  if (lane == 0) {
#pragma unroll
    for (int j = 0; j < JPW; ++j)
      doutb[r0 + j] = sqrtf(wc[j] / sm[j]);
  }
}

__device__ __forceinline__ float blk_sum512(float v, float* lds) {
#pragma unroll
  for (int off = 32; off >= 1; off >>= 1) v += __shfl_xor(v, off, 64);
  int lane = threadIdx.x & 63, wv = threadIdx.x >> 6;
  __syncthreads();
  if (lane == 0) lds[wv] = v;
  __syncthreads();
  return lds[0]+lds[1]+lds[2]+lds[3]+lds[4]+lds[5]+lds[6]+lds[7];
}

__device__ __forceinline__ void finalize_body(int b,
    const float* __restrict__ A, const float* __restrict__ B,
    const float* __restrict__ C, const float* __restrict__ D,
    const float* __restrict__ dv1, const float* __restrict__ dv2,
    float* __restrict__ out, float* lds) {
  const int t = threadIdx.x;
  float e1 = 0, e2 = 0;
  for (int i = t; i < 1024; i += 512) e1 += dv1[b*1024+i];
  e1 = blk_sum512(e1, lds);
  for (int i = t; i < 4096; i += 512) e2 += dv2[b*4096+i];
  e2 = blk_sum512(e2, lds);
  float rA=0, sA=0, rB=0, sB=0, rC=0, sC=0, rD=0, sD=0;
  for (int i = t; i < 4096; i += 512) { float v = A[b*4096+i]; rA += v; sA += sqrtf(v); }
  rA = blk_sum512(rA, lds); sA = blk_sum512(sA, lds);
  for (int i = t; i < 512;  i += 512) { float v = B[b*512+i];  rB += v; sB += sqrtf(v); }
  rB = blk_sum512(rB, lds); sB = blk_sum512(sB, lds);
  for (int i = t; i < 4096; i += 512) { float v = C[b*4096+i]; rC += v; sC += sqrtf(v); }
  rC = blk_sum512(rC, lds); sC = blk_sum512(sC, lds);
  for (int i = t; i < 4096; i += 512) { float v = D[b*4096+i]; rD += v; sD += sqrtf(v); }
  rD = blk_sum512(rD, lds); sD = blk_sum512(sD, lds);
  if (t == 0) {
    out[27648 + b] = e1 / 1024.0f;
    out[27650 + b] = e2 / 4096.0f;
    out[27652 + b] = 0.5f*(sA/4096.0f + sB/512.0f);
    out[27654 + b] = 0.5f*(sC/4096.0f + sD/4096.0f);
    out[27656 + b] = rA/4096.0f + rB/512.0f;
    out[27658 + b] = rC/4096.0f + rD/4096.0f;
  }
}

// ---- tiny init: zero the 8 sync words (replay-safe) ----
__global__ void init_sync(unsigned* __restrict__ sync) {
  if (threadIdx.x < 8)
    __hip_atomic_store(&sync[threadIdx.x], 0u, __ATOMIC_RELAXED, __HIP_MEMORY_SCOPE_AGENT);
}

// ===================== the one big kernel: 194 blocks x 512 ====================
// blk 0-1: FPS | blk 2-129: EMD2 persistent (128 x 64 rows)
// blk 130-193: chamfer(50)/copies(14) first, then EMD1 (64 x 32 rows), finalize
__global__ __launch_bounds__(512) void everything(
    const float* __restrict__ coarse, const float* __restrict__ fine,
    const float* __restrict__ gt, const int* __restrict__ itersPtr,
    float* __restrict__ chamA, float* __restrict__ chamB,
    float* __restrict__ chamC, float* __restrict__ chamD,
    float* __restrict__ f1, float* __restrict__ g1, float* __restrict__ dv1,
    float* __restrict__ f2, float* __restrict__ g2, float* __restrict__ dv2,
    float* __restrict__ gtfps, unsigned* __restrict__ sync,
    float* __restrict__ out) {
  __shared__ Lds L;
  const int blk = blockIdx.x;
  const int t = threadIdx.x;
  unsigned* cnt1 = &sync[0]; unsigned* gen1 = &sync[1];
  unsigned* cnt2 = &sync[2]; unsigned* gen2 = &sync[3];
  unsigned* fpsflag = &sync[4];            // [4],[5] per batch
  unsigned* done2 = &sync[6]; unsigned* chamdone = &sync[7];

  if (blk < 2) {                                       // ---------------- FPS
    fps_body(L, gt, gtfps, blk);
    signal_done(&fpsflag[blk]);
    return;
  }
  if (blk < 130) {                                     // ---------------- EMD2
    const int eb = blk - 2;
    const int b = eb >> 6, bxl = eb & 63;
    const int r0b = bxl * 64;
    const int iters = *itersPtr;
    const float* fb = fine + (size_t)b*4096*3;
    const float* gb = gt   + (size_t)b*4096*3;
    float* f2b = f2 + b*4096; float* g2b = g2 + b*4096; float* dv2b = dv2 + b*4096;
    for (int ph = 0; ph < 8; ++ph) {
      const int k = ph >> 1;
      if (k < iters) {
        if (!(ph & 1))
          emd_pass_t<8>(fb, 4095, gb, 4095, g2b, f2b, 4096, LOGN2, k > 0, r0b,
                        L.emd.tyx, L.emd.tyy, L.emd.tyz, L.emd.tg);
        else
          emd_pass_t<8>(gb, 4095, fb, 4095, f2b, g2b, 4096, LOGN2, 1, r0b,
                        L.emd.tyx, L.emd.tyy, L.emd.tyz, L.emd.tg);
      }
      gbar(cnt2, gen2, 128u);
    }
    emd_final_t<8>(fb, 4095, gb, 4095, g2b, dv2b, 4096, iters > 0, r0b,
                   L.emd.tyx, L.emd.tyy, L.emd.tyz, L.emd.tg);
    signal_done(done2);
    return;
  }
  // ---------------- EMD1 group: chamfer/copies first, then EMD1, then finalize ----
  {
    const int eb = blk - 130;
    if (eb < 50) {                                     // -------- chamfer (during FPS)
      const int cid = eb;
      const float *q, *tp; float* om; int nq, nt, cb2, qx;
      if (cid < 16)      { cb2 = cid>>3;        qx = cid&7; q = gt;     nq = 4096; tp = coarse; nt = 512;  om = chamA; }
      else if (cid < 18) { cb2 = cid-16;        qx = 0;     q = coarse; nq = 512;  tp = gt;     nt = 4096; om = chamB; }
      else if (cid < 34) { int r = cid-18; cb2 = r>>3; qx = r&7; q = gt;   nq = 4096; tp = fine; nt = 4096; om = chamC; }
      else               { int r = cid-34; cb2 = r>>3; qx = r&7; q = fine; nq = 4096; tp = gt;   nt = 4096; om = chamD; }
      const int qi = qx*512 + t;
      const float* qp = q + (size_t)(cb2*nq + qi)*3;
      float qxv = qp[0], qyv = qp[1], qzv = qp[2];
      float m = 3.4e38f;
      for (int tt0 = 0; tt0 < nt; tt0 += 1024) {
        int chunk = min(1024, nt - tt0);
        __syncthreads();
        for (int i = t; i < chunk; i += 512) {
          const float* pp = tp + (size_t)(cb2*nt + tt0 + i)*3;
          L.ch.x[i] = pp[0]; L.ch.y[i] = pp[1]; L.ch.z[i] = pp[2];
        }
        __syncthreads();
        for (int i = 0; i < chunk; ++i) {
          float dx = qxv-L.ch.x[i], dy = qyv-L.ch.y[i], dz = qzv-L.ch.z[i];
          float d = dx*dx + dy*dy + dz*dz;
          m = fminf(m, d);
        }
      }
      om[cb2*nq + qi] = m;
      signal_done(chamdone);
    } else {                                           // -------- output copies
      for (int i = (eb - 50)*512 + t; i < 27648; i += 14*512)
        out[i] = (i < 3072) ? coarse[i] : fine[i - 3072];
    }
    // -------- EMD1: 64 blocks x 32 rows --------
    const int b = eb >> 5, bxl = eb & 31;
    const int r0b = bxl * 32;
    const int iters = *itersPtr;
    const float* cb = coarse + (size_t)b*512*3;        // xtile == coarse with &511 wrap
    const float* pb = gtfps  + (size_t)b*1024*3;
    float* f1b = f1 + b*1024; float* g1b = g1 + b*1024; float* dv1b = dv1 + b*1024;
    waitcnt_ge(&fpsflag[b], 1u);                       // gtfps ready
    for (int ph = 0; ph < 8; ++ph) {
      const int k = ph >> 1;
      if (k < iters) {
        if (!(ph & 1))
          emd_pass_t<4>(cb, 511, pb, 1023, g1b, f1b, 1024, LOGN1, k > 0, r0b,
                        L.emd.tyx, L.emd.tyy, L.emd.tyz, L.emd.tg);
        else
          emd_pass_t<4>(pb, 1023, cb, 511, f1b, g1b, 1024, LOGN1, 1, r0b,
                        L.emd.tyx, L.emd.tyy, L.emd.tyz, L.emd.tg);
      }
      gbar(cnt1, gen1, 64u);
    }
    emd_final_t<4>(cb, 511, pb, 1023, g1b, dv1b, 1024, iters > 0, r0b,
                   L.emd.tyx, L.emd.tyy, L.emd.tyz, L.emd.tg);
    gbar(cnt1, gen1, 64u);                             // dv1 complete
    if (bxl == 0) {                                    // one finalizer per batch
      waitcnt_ge(done2, 128u);                         // dv2 complete
      waitcnt_ge(chamdone, 50u);                       // chamA-D complete
      finalize_body(b, chamA, chamB, chamC, chamD, dv1, dv2, out, L.emd.tyx);
    }
  }
}

extern "C" void kernel_launch(void* const* d_in, const int* in_sizes, int n_in,
                              void* d_out, int out_size, void* d_ws, size_t ws_size,
                              hipStream_t stream) {
  (void)in_sizes; (void)n_in; (void)out_size; (void)ws_size;
  const float* coarse = (const float*)d_in[0];
  const float* fine   = (const float*)d_in[1];
  const float* gt     = (const float*)d_in[2];
  const int*   iters  = (const int*)d_in[3];
  float* out = (float*)d_out;
  float* ws  = (float*)d_ws;

  float* chamA = ws + 0;        // 2*4096
  float* chamB = ws + 8192;     // 2*512
  float* chamC = ws + 9216;     // 2*4096
  float* chamD = ws + 17408;    // 2*4096
  float* f1    = ws + 25600;    // 2*1024
  float* g1    = ws + 27648;    // 2*1024
  float* dv1   = ws + 29696;    // 2*1024
  float* f2    = ws + 31744;    // 2*4096
  float* g2    = ws + 39936;    // 2*4096
  float* dv2   = ws + 48128;    // 2*4096
  float* gtfps = ws + 56320;    // 2*1024*3
  unsigned* sync = (unsigned*)(ws + 62464);  // 8 words

  init_sync<<<1, 64, 0, stream>>>(sync);
  everything<<<194, 512, 0, stream>>>(coarse, fine, gt, iters,
                                      chamA, chamB, chamC, chamD,
                                      f1, g1, dv1, f2, g2, dv2,
                                      gtfps, sync, out);
}

// Round 14
// 969.027 us; speedup vs baseline: 1.4359x; 1.4359x over previous
//
#include <hip/hip_runtime.h>
#include <math.h>

static constexpr float EPS_SK = 0.02f;
static constexpr float LOG2E  = 1.4426950408889634f;
static constexpr float LN2F   = 0.6931471805599453f;
#define LOGN1 6.931471805599453f   /* log 1024 */
#define LOGN2 8.317766166719343f   /* log 4096 */

__device__ __forceinline__ float fexp2(float x){ return __builtin_amdgcn_exp2f(x); }
__device__ __forceinline__ float flog2(float x){ return __builtin_amdgcn_logf(x); }

using f32x2 = __attribute__((ext_vector_type(2))) float;

// ============ LDS union padded >80KB => exactly 1 block/CU; 194 blocks co-resident ====
union Lds {
  struct {
    float sx[4096], sy[4096], sz[4096];      // 48 KB staged points (SoA for pk loads)
    float obx[1024], oby[1024], obz[1024];   // 12 KB selected-point buffer
    unsigned long long sl[2][8];             // parity-double-buffered wave winners
  } fps;
  struct { float tyx[1024], tyy[1024], tyz[1024], tg[1024]; } emd;
  struct { float x[1024], y[1024], z[1024]; } ch;
  float pad[21000];                          // 84000 B -> 1 block/CU
};

// ---------------- sync primitives (validated R5-R13) ----------------
__device__ __forceinline__ void gbar(unsigned* cnt, unsigned* gen, unsigned nblk) {
  __threadfence();
  __syncthreads();
  if (threadIdx.x == 0) {
    unsigned g = __hip_atomic_load(gen, __ATOMIC_ACQUIRE, __HIP_MEMORY_SCOPE_AGENT);
    if (__hip_atomic_fetch_add(cnt, 1u, __ATOMIC_ACQ_REL, __HIP_MEMORY_SCOPE_AGENT) == nblk - 1u) {
      __hip_atomic_store(cnt, 0u, __ATOMIC_RELAXED, __HIP_MEMORY_SCOPE_AGENT);
      __hip_atomic_fetch_add(gen, 1u, __ATOMIC_ACQ_REL, __HIP_MEMORY_SCOPE_AGENT);
    } else {
      while (__hip_atomic_load(gen, __ATOMIC_ACQUIRE, __HIP_MEMORY_SCOPE_AGENT) == g)
        __builtin_amdgcn_s_sleep(8);
    }
  }
  __syncthreads();
  __threadfence();
}

__device__ __forceinline__ void signal_done(unsigned* f) {
  __threadfence();
  __syncthreads();
  if (threadIdx.x == 0)
    __hip_atomic_fetch_add(f, 1u, __ATOMIC_RELEASE, __HIP_MEMORY_SCOPE_AGENT);
}

__device__ __forceinline__ void waitcnt_ge(unsigned* f, unsigned target) {
  if (threadIdx.x == 0)
    while (__hip_atomic_load(f, __ATOMIC_ACQUIRE, __HIP_MEMORY_SCOPE_AGENT) < target)
      __builtin_amdgcn_s_sleep(16);
  __syncthreads();
  __threadfence();
}

// DPP helper (old=self => invalid lanes are no-ops); chain accumulates to lane 63
template<int C>
__device__ __forceinline__ float dppf(float x) {
  return __int_as_float(__builtin_amdgcn_update_dpp(
      __float_as_int(x), __float_as_int(x), C, 0xF, 0xF, false));
}
__device__ __forceinline__ float wave_max_to_l63(float v) {
  v = fmaxf(v, dppf<0x111>(v));  // row_shr:1
  v = fmaxf(v, dppf<0x112>(v));  // row_shr:2
  v = fmaxf(v, dppf<0x114>(v));  // row_shr:4
  v = fmaxf(v, dppf<0x118>(v));  // row_shr:8
  v = fmaxf(v, dppf<0x142>(v));  // row_bcast15
  v = fmaxf(v, dppf<0x143>(v));  // row_bcast31
  return v;
}
__device__ __forceinline__ unsigned long long u64max(unsigned long long a, unsigned long long b) {
  return a > b ? a : b;
}

// ---------------- FPS body: 512 threads (8 waves), 8 pts/lane as 4 f32x2 pairs ------
// pk distance update + value-only DPP max + ballot/ff1/readlane index resolve.
// Lane index ranges are disjoint ascending => first matching lane = wave-min index.
__device__ __forceinline__ void fps_body(Lds& L, const float* __restrict__ gt,
                                         float* __restrict__ gt_fps, int b) {
  const int t = threadIdx.x;
  const int lane = t & 63;
  const int wv   = t >> 6;
  const float* P = gt + (size_t)b*4096*3;
  for (int i = t; i < 4096; i += 512) {
    L.fps.sx[i] = P[i*3+0]; L.fps.sy[i] = P[i*3+1]; L.fps.sz[i] = P[i*3+2];
  }
  __syncthreads();
  // global idx = t*8 + 2*p + half  (ascending in (p, half) for fixed t)
  f32x2 px[4], py[4], pz[4], d2[4];
#pragma unroll
  for (int p = 0; p < 4; ++p) {
    const int i0 = t*8 + 2*p;
    px[p] = *(const f32x2*)&L.fps.sx[i0];
    py[p] = *(const f32x2*)&L.fps.sy[i0];
    pz[p] = *(const f32x2*)&L.fps.sz[i0];
    d2[p].x = 1e10f; d2[p].y = 1e10f;        // matches reference init
  }
  float cx = L.fps.sx[0], cy = L.fps.sy[0], cz = L.fps.sz[0];
  if (t == 0) { L.fps.obx[0] = cx; L.fps.oby[0] = cy; L.fps.obz[0] = cz; }
  for (int s = 1; s < 1024; ++s) {
    f32x2 nd0, nd1, nd2, nd3;
    {
#pragma clang fp contract(off)
      f32x2 c2x; c2x.x = cx; c2x.y = cx;
      f32x2 c2y; c2y.x = cy; c2y.y = cy;
      f32x2 c2z; c2z.x = cz; c2z.y = cz;
      f32x2 dx, dy, dz, d;
      dx = px[0]-c2x; dy = py[0]-c2y; dz = pz[0]-c2z;
      d = dx*dx + dy*dy + dz*dz;  nd0 = __builtin_elementwise_min(d2[0], d); d2[0] = nd0;
      dx = px[1]-c2x; dy = py[1]-c2y; dz = pz[1]-c2z;
      d = dx*dx + dy*dy + dz*dz;  nd1 = __builtin_elementwise_min(d2[1], d); d2[1] = nd1;
      dx = px[2]-c2x; dy = py[2]-c2y; dz = pz[2]-c2z;
      d = dx*dx + dy*dy + dz*dz;  nd2 = __builtin_elementwise_min(d2[2], d); d2[2] = nd2;
      dx = px[3]-c2x; dy = py[3]-c2y; dz = pz[3]-c2z;
      d = dx*dx + dy*dy + dz*dz;  nd3 = __builtin_elementwise_min(d2[3], d); d2[3] = nd3;
    }
    // tree-shaped running max (3-deep instead of 4-deep chain)
    f32x2 m01 = __builtin_elementwise_max(nd0, nd1);
    f32x2 m23 = __builtin_elementwise_max(nd2, nd3);
    f32x2 m03 = __builtin_elementwise_max(m01, m23);
    float bv = fmaxf(m03.x, m03.y);
    bv = wave_max_to_l63(bv);
    const unsigned Mbits = (unsigned)__builtin_amdgcn_readlane(__float_as_int(bv), 63);
    const float M = __uint_as_float(Mbits);
    // per-lane first-match index (local indices ascend with (p,half))
    int icl = 0x7FFFFFFF;
#pragma unroll
    for (int p = 0; p < 4; ++p) {
      const int i0 = t*8 + 2*p;
      if (d2[p].x == M) icl = min(icl, i0);
      if (d2[p].y == M) icl = min(icl, i0 + 1);
    }
    // first lane with a match holds the smallest matching global idx (disjoint ranges)
    unsigned long long mk = __ballot(icl != 0x7FFFFFFF);
    const int sl0 = __builtin_ctzll(mk);               // SGPR via s_ff1
    const int widx = __builtin_amdgcn_readlane(icl, sl0);
    const int pb = s & 1;
    if (lane == 0)
      L.fps.sl[pb][wv] = (((unsigned long long)Mbits) << 32)
                         | (unsigned)(~widx); // bigger packed = bigger val or smaller idx
    __syncthreads();
    ulonglong2 a0 = *(const ulonglong2*)&L.fps.sl[pb][0];
    ulonglong2 a1 = *(const ulonglong2*)&L.fps.sl[pb][2];
    ulonglong2 a2 = *(const ulonglong2*)&L.fps.sl[pb][4];
    ulonglong2 a3 = *(const ulonglong2*)&L.fps.sl[pb][6];
    unsigned long long m0 = u64max(a0.x, a0.y);
    unsigned long long m1 = u64max(a1.x, a1.y);
    unsigned long long m2 = u64max(a2.x, a2.y);
    unsigned long long m3 = u64max(a3.x, a3.y);
    unsigned long long bp = u64max(u64max(m0, m1), u64max(m2, m3));
    int idxw = (int)(~(unsigned)bp);
    cx = L.fps.sx[idxw]; cy = L.fps.sy[idxw]; cz = L.fps.sz[idxw];  // broadcast reads
    if (t == 0) { L.fps.obx[s] = cx; L.fps.oby[s] = cy; L.fps.obz[s] = cz; }
  }
  __syncthreads();
  for (int i = t; i < 1024; i += 512) {      // one bulk global store at the end
    float* o = gt_fps + (size_t)(b*1024 + i)*3;
    o[0] = L.fps.obx[i]; o[1] = L.fps.oby[i]; o[2] = L.fps.obz[i];
  }
}

// ============== EMD bodies, 512 threads, JPW rows/wave, masked row wrap (proven) ====
template<int JPW>
__device__ __forceinline__ void emd_pass_t(
    const float* __restrict__ xb, int xm,
    const float* __restrict__ yb, int ym,
    const float* __restrict__ vinb, float* __restrict__ voutb,
    int N, float logN, int use_vin, int r0b,
    float* tyx, float* tyy, float* tyz, float* tg)
{
  const int t = threadIdx.x;
  const int lane = t & 63;
  const int wv   = t >> 6;
  const int r0 = r0b + wv*JPW;
  float px[JPW], py[JPW], pz[JPW], mx[JPW], sm[JPW];
#pragma unroll
  for (int j = 0; j < JPW; ++j) {
    const int row = (r0 + j) & xm;
    const float* xp = xb + (size_t)row*3;
    px[j] = xp[0]; py[j] = xp[1]; pz[j] = xp[2];
    mx[j] = -3.4e38f; sm[j] = 0.0f;
  }
  const float S = LOG2E / EPS_SK;
  const int ntiles = N >> 10;
  for (int tt = 0; tt < ntiles; ++tt) {
    const int base = tt << 10;
    __syncthreads();
    for (int i = t; i < 1024; i += 512) {
      const int row = (base + i) & ym;
      const float* yp = yb + (size_t)row*3;
      tyx[i] = yp[0]; tyy[i] = yp[1]; tyz[i] = yp[2];
      tg[i]  = use_vin ? vinb[base + i] : 0.0f;
    }
    __syncthreads();
    for (int mi = lane; mi < 1024; mi += 64) {
      float yx = tyx[mi], yy = tyy[mi], yz = tyz[mi], g = tg[mi];
#pragma unroll
      for (int j = 0; j < JPW; ++j) {
        float dx = px[j]-yx, dy = py[j]-yy, dz = pz[j]-yz;
        float d  = dx*dx + dy*dy + dz*dz;
        float tv = (g - d) * S;
        float nm = fmaxf(mx[j], tv);
        sm[j] = sm[j]*fexp2(mx[j]-nm) + fexp2(tv-nm);
        mx[j] = nm;
      }
    }
  }
#pragma unroll
  for (int j = 0; j < JPW; ++j) {
#pragma unroll
    for (int off = 1; off < 64; off <<= 1) {
      float om = __shfl_xor(mx[j], off, 64);
      float os = __shfl_xor(sm[j], off, 64);
      float nm = fmaxf(mx[j], om);
      sm[j] = sm[j]*fexp2(mx[j]-nm) + os*fexp2(om-nm);
      mx[j] = nm;
    }
  }
  if (lane == 0) {
#pragma unroll
    for (int j = 0; j < JPW; ++j) {
      float lse = (mx[j] + flog2(sm[j])) * LN2F;
      voutb[r0 + j] = -EPS_SK * (lse + logN);
    }
  }
}

template<int JPW>
__device__ __forceinline__ void emd_final_t(
    const float* __restrict__ xb, int xm,
    const float* __restrict__ yb, int ym,
    const float* __restrict__ ginb, float* __restrict__ doutb,
    int N, int use_g, int r0b,
    float* tyx, float* tyy, float* tyz, float* tg)
{
  const int t = threadIdx.x;
  const int lane = t & 63;
  const int wv   = t >> 6;
  const int r0 = r0b + wv*JPW;
  float px[JPW], py[JPW], pz[JPW], mx[JPW], sm[JPW], wc[JPW];
#pragma unroll
  for (int j = 0; j < JPW; ++j) {
    const int row = (r0 + j) & xm;
    const float* xp = xb + (size_t)row*3;
    px[j] = xp[0]; py[j] = xp[1]; pz[j] = xp[2];
    mx[j] = -3.4e38f; sm[j] = 0.0f; wc[j] = 0.0f;
  }
  const float S = LOG2E / EPS_SK;
  const int ntiles = N >> 10;
  for (int tt = 0; tt < ntiles; ++tt) {
    const int base = tt << 10;
    __syncthreads();
    for (int i = t; i < 1024; i += 512) {
      const int row = (base + i) & ym;
      const float* yp = yb + (size_t)row*3;
      tyx[i] = yp[0]; tyy[i] = yp[1]; tyz[i] = yp[2];
      tg[i]  = use_g ? ginb[base + i] : 0.0f;
    }
    __syncthreads();
    for (int mi = lane; mi < 1024; mi += 64) {
      float yx = tyx[mi], yy = tyy[mi], yz = tyz[mi], g = tg[mi];
#pragma unroll
      for (int j = 0; j < JPW; ++j) {
        float dx = px[j]-yx, dy = py[j]-yy, dz = pz[j]-yz;
        float d  = dx*dx + dy*dy + dz*dz;
        float tv = (g - d) * S;
        float nm = fmaxf(mx[j], tv);
        float r  = fexp2(mx[j]-nm);
        float e  = fexp2(tv-nm);
        sm[j] = sm[j]*r + e;
        wc[j] = wc[j]*r + e*d;
        mx[j] = nm;
      }
    }
  }
#pragma unroll
  for (int j = 0; j < JPW; ++j) {
#pragma unroll
    for (int off = 1; off < 64; off <<= 1) {
      float om = __shfl_xor(mx[j], off, 64);
      float os = __shfl_xor(sm[j], off, 64);
      float ow = __shfl_xor(wc[j], off, 64);
      float nm = fmaxf(mx[j], om);
      float r1 = fexp2(mx[j]-nm);
      float r2 = fexp2(om-nm);
      sm[j] = sm[j]*r1 + os*r2;
      wc[j] = wc[j]*r1 + ow*r2;
      mx[j] = nm;
    }
  }
  if (lane == 0) {
#pragma unroll
    for (int j = 0; j < JPW; ++j)
      doutb[r0 + j] = sqrtf(wc[j] / sm[j]);
  }
}

__device__ __forceinline__ float blk_sum512(float v, float* lds) {
#pragma unroll
  for (int off = 32; off >= 1; off >>= 1) v += __shfl_xor(v, off, 64);
  int lane = threadIdx.x & 63, wv = threadIdx.x >> 6;
  __syncthreads();
  if (lane == 0) lds[wv] = v;
  __syncthreads();
  return lds[0]+lds[1]+lds[2]+lds[3]+lds[4]+lds[5]+lds[6]+lds[7];
}

__device__ __forceinline__ void finalize_body(int b,
    const float* __restrict__ A, const float* __restrict__ B,
    const float* __restrict__ C, const float* __restrict__ D,
    const float* __restrict__ dv1, const float* __restrict__ dv2,
    float* __restrict__ out, float* lds) {
  const int t = threadIdx.x;
  float e1 = 0, e2 = 0;
  for (int i = t; i < 1024; i += 512) e1 += dv1[b*1024+i];
  e1 = blk_sum512(e1, lds);
  for (int i = t; i < 4096; i += 512) e2 += dv2[b*4096+i];
  e2 = blk_sum512(e2, lds);
  float rA=0, sA=0, rB=0, sB=0, rC=0, sC=0, rD=0, sD=0;
  for (int i = t; i < 4096; i += 512) { float v = A[b*4096+i]; rA += v; sA += sqrtf(v); }
  rA = blk_sum512(rA, lds); sA = blk_sum512(sA, lds);
  for (int i = t; i < 512;  i += 512) { float v = B[b*512+i];  rB += v; sB += sqrtf(v); }
  rB = blk_sum512(rB, lds); sB = blk_sum512(sB, lds);
  for (int i = t; i < 4096; i += 512) { float v = C[b*4096+i]; rC += v; sC += sqrtf(v); }
  rC = blk_sum512(rC, lds); sC = blk_sum512(sC, lds);
  for (int i = t; i < 4096; i += 512) { float v = D[b*4096+i]; rD += v; sD += sqrtf(v); }
  rD = blk_sum512(rD, lds); sD = blk_sum512(sD, lds);
  if (t == 0) {
    out[27648 + b] = e1 / 1024.0f;
    out[27650 + b] = e2 / 4096.0f;
    out[27652 + b] = 0.5f*(sA/4096.0f + sB/512.0f);
    out[27654 + b] = 0.5f*(sC/4096.0f + sD/4096.0f);
    out[27656 + b] = rA/4096.0f + rB/512.0f;
    out[27658 + b] = rC/4096.0f + rD/4096.0f;
  }
}

// ---- tiny init: zero the 8 sync words (replay-safe) ----
__global__ void init_sync(unsigned* __restrict__ sync) {
  if (threadIdx.x < 8)
    __hip_atomic_store(&sync[threadIdx.x], 0u, __ATOMIC_RELAXED, __HIP_MEMORY_SCOPE_AGENT);
}

// ===================== the one big kernel: 194 blocks x 512 ====================
// blk 0-1: FPS | blk 2-129: EMD2 persistent (128 x 64 rows)
// blk 130-193: chamfer(50)/copies(14) first, then EMD1 (64 x 32 rows), finalize
__global__ __launch_bounds__(512) void everything(
    const float* __restrict__ coarse, const float* __restrict__ fine,
    const float* __restrict__ gt, const int* __restrict__ itersPtr,
    float* __restrict__ chamA, float* __restrict__ chamB,
    float* __restrict__ chamC, float* __restrict__ chamD,
    float* __restrict__ f1, float* __restrict__ g1, float* __restrict__ dv1,
    float* __restrict__ f2, float* __restrict__ g2, float* __restrict__ dv2,
    float* __restrict__ gtfps, unsigned* __restrict__ sync,
    float* __restrict__ out) {
  __shared__ Lds L;
  const int blk = blockIdx.x;
  const int t = threadIdx.x;
  unsigned* cnt1 = &sync[0]; unsigned* gen1 = &sync[1];
  unsigned* cnt2 = &sync[2]; unsigned* gen2 = &sync[3];
  unsigned* fpsflag = &sync[4];            // [4],[5] per batch
  unsigned* done2 = &sync[6]; unsigned* chamdone = &sync[7];

  if (blk < 2) {                                       // ---------------- FPS
    fps_body(L, gt, gtfps, blk);
    signal_done(&fpsflag[blk]);
    return;
  }
  if (blk < 130) {                                     // ---------------- EMD2
    const int eb = blk - 2;
    const int b = eb >> 6, bxl = eb & 63;
    const int r0b = bxl * 64;
    const int iters = *itersPtr;
    const float* fb = fine + (size_t)b*4096*3;
    const float* gb = gt   + (size_t)b*4096*3;
    float* f2b = f2 + b*4096; float* g2b = g2 + b*4096; float* dv2b = dv2 + b*4096;
    for (int ph = 0; ph < 8; ++ph) {
      const int k = ph >> 1;
      if (k < iters) {
        if (!(ph & 1))
          emd_pass_t<8>(fb, 4095, gb, 4095, g2b, f2b, 4096, LOGN2, k > 0, r0b,
                        L.emd.tyx, L.emd.tyy, L.emd.tyz, L.emd.tg);
        else
          emd_pass_t<8>(gb, 4095, fb, 4095, f2b, g2b, 4096, LOGN2, 1, r0b,
                        L.emd.tyx, L.emd.tyy, L.emd.tyz, L.emd.tg);
      }
      gbar(cnt2, gen2, 128u);
    }
    emd_final_t<8>(fb, 4095, gb, 4095, g2b, dv2b, 4096, iters > 0, r0b,
                   L.emd.tyx, L.emd.tyy, L.emd.tyz, L.emd.tg);
    signal_done(done2);
    return;
  }
  // ---------------- EMD1 group: chamfer/copies first, then EMD1, then finalize ----
  {
    const int eb = blk - 130;
    if (eb < 50) {                                     // -------- chamfer (during FPS)
      const int cid = eb;
      const float *q, *tp; float* om; int nq, nt, cb2, qx;
      if (cid < 16)      { cb2 = cid>>3;        qx = cid&7; q = gt;     nq = 4096; tp = coarse; nt = 512;  om = chamA; }
      else if (cid < 18) { cb2 = cid-16;        qx = 0;     q = coarse; nq = 512;  tp = gt;     nt = 4096; om = chamB; }
      else if (cid < 34) { int r = cid-18; cb2 = r>>3; qx = r&7; q = gt;   nq = 4096; tp = fine; nt = 4096; om = chamC; }
      else               { int r = cid-34; cb2 = r>>3; qx = r&7; q = fine; nq = 4096; tp = gt;   nt = 4096; om = chamD; }
      const int qi = qx*512 + t;
      const float* qp = q + (size_t)(cb2*nq + qi)*3;
      float qxv = qp[0], qyv = qp[1], qzv = qp[2];
      float m = 3.4e38f;
      for (int tt0 = 0; tt0 < nt; tt0 += 1024) {
        int chunk = min(1024, nt - tt0);
        __syncthreads();
        for (int i = t; i < chunk; i += 512) {
          const float* pp = tp + (size_t)(cb2*nt + tt0 + i)*3;
          L.ch.x[i] = pp[0]; L.ch.y[i] = pp[1]; L.ch.z[i] = pp[2];
        }
        __syncthreads();
        for (int i = 0; i < chunk; ++i) {
          float dx = qxv-L.ch.x[i], dy = qyv-L.ch.y[i], dz = qzv-L.ch.z[i];
          float d = dx*dx + dy*dy + dz*dz;
          m = fminf(m, d);
        }
      }
      om[cb2*nq + qi] = m;
      signal_done(chamdone);
    } else {                                           // -------- output copies
      for (int i = (eb - 50)*512 + t; i < 27648; i += 14*512)
        out[i] = (i < 3072) ? coarse[i] : fine[i - 3072];
    }
    // -------- EMD1: 64 blocks x 32 rows --------
    const int b = eb >> 5, bxl = eb & 31;
    const int r0b = bxl * 32;
    const int iters = *itersPtr;
    const float* cb = coarse + (size_t)b*512*3;        // xtile == coarse with &511 wrap
    const float* pb = gtfps  + (size_t)b*1024*3;
    float* f1b = f1 + b*1024; float* g1b = g1 + b*1024; float* dv1b = dv1 + b*1024;
    waitcnt_ge(&fpsflag[b], 1u);                       // gtfps ready
    for (int ph = 0; ph < 8; ++ph) {
      const int k = ph >> 1;
      if (k < iters) {
        if (!(ph & 1))
          emd_pass_t<4>(cb, 511, pb, 1023, g1b, f1b, 1024, LOGN1, k > 0, r0b,
                        L.emd.tyx, L.emd.tyy, L.emd.tyz, L.emd.tg);
        else
          emd_pass_t<4>(pb, 1023, cb, 511, f1b, g1b, 1024, LOGN1, 1, r0b,
                        L.emd.tyx, L.emd.tyy, L.emd.tyz, L.emd.tg);
      }
      gbar(cnt1, gen1, 64u);
    }
    emd_final_t<4>(cb, 511, pb, 1023, g1b, dv1b, 1024, iters > 0, r0b,
                   L.emd.tyx, L.emd.tyy, L.emd.tyz, L.emd.tg);
    gbar(cnt1, gen1, 64u);                             // dv1 complete
    if (bxl == 0) {                                    // one finalizer per batch
      waitcnt_ge(done2, 128u);                         // dv2 complete
      waitcnt_ge(chamdone, 50u);                       // chamA-D complete
      finalize_body(b, chamA, chamB, chamC, chamD, dv1, dv2, out, L.emd.tyx);
    }
  }
}

extern "C" void kernel_launch(void* const* d_in, const int* in_sizes, int n_in,
                              void* d_out, int out_size, void* d_ws, size_t ws_size,
                              hipStream_t stream) {
  (void)in_sizes; (void)n_in; (void)out_size; (void)ws_size;
  const float* coarse = (const float*)d_in[0];
  const float* fine   = (const float*)d_in[1];
  const float* gt     = (const float*)d_in[2];
  const int*   iters  = (const int*)d_in[3];
  float* out = (float*)d_out;
  float* ws  = (float*)d_ws;

  float* chamA = ws + 0;        // 2*4096
  float* chamB = ws + 8192;     // 2*512
  float* chamC = ws + 9216;     // 2*4096
  float* chamD = ws + 17408;    // 2*4096
  float* f1    = ws + 25600;    // 2*1024
  float* g1    = ws + 27648;    // 2*1024
  float* dv1   = ws + 29696;    // 2*1024
  float* f2    = ws + 31744;    // 2*4096
  float* g2    = ws + 39936;    // 2*4096
  float* dv2   = ws + 48128;    // 2*4096
  float* gtfps = ws + 56320;    // 2*1024*3
  unsigned* sync = (unsigned*)(ws + 62464);  // 8 words

  init_sync<<<1, 64, 0, stream>>>(sync);
  everything<<<194, 512, 0, stream>>>(coarse, fine, gt, iters,
                                      chamA, chamB, chamC, chamD,
                                      f1, g1, dv1, f2, g2, dv2,
                                      gtfps, sync, out);
}